// Round 10
// baseline (1718.837 us; speedup 1.0000x reference)
//
#include <hip/hip_runtime.h>
#include <hip/hip_bf16.h>
#include <cstdint>
#include <cstddef>

#define GN 100000
#define GE 3200000

typedef __attribute__((ext_vector_type(8))) _Float16 f16x8;
typedef __attribute__((ext_vector_type(4))) _Float16 f16x4;
typedef __attribute__((ext_vector_type(4))) float f32x4;
typedef __attribute__((ext_vector_type(2))) int i32x2;   // NT-safe 8B edge pair

// ---------------- CSR build ----------------

__global__ void k_zero(int* __restrict__ p, int n) {
    int i = blockIdx.x * blockDim.x + threadIdx.x;
    if (i < n) p[i] = 0;
}

__global__ void k_hist(const int* __restrict__ dst, int* __restrict__ cnt, int e) {
    for (int i = blockIdx.x * blockDim.x + threadIdx.x; i < e; i += gridDim.x * blockDim.x)
        atomicAdd(&cnt[dst[i]], 1);
}

__global__ void k_chunksum(const int* __restrict__ cnt, int* __restrict__ bsum, int n) {
    __shared__ int s[256];
    int b = blockIdx.x, t = threadIdx.x;
    int i0 = b * 512;
    int v = 0;
    int i1 = i0 + t;        if (i1 < n) v += cnt[i1];
    int i2 = i0 + 256 + t;  if (i2 < n) v += cnt[i2];
    s[t] = v; __syncthreads();
    for (int d = 128; d > 0; d >>= 1) {
        if (t < d) s[t] += s[t + d];
        __syncthreads();
    }
    if (t == 0) bsum[b] = s[0];
}

__global__ void k_scanb(const int* __restrict__ bsum, int* __restrict__ boff, int nb,
                        int* __restrict__ row_ptr, int n) {
    if (threadIdx.x == 0 && blockIdx.x == 0) {
        int acc = 0;
        for (int b = 0; b < nb; b++) { boff[b] = acc; acc += bsum[b]; }
        row_ptr[n] = acc;
    }
}

__global__ void k_scanw(const int* __restrict__ cnt, const int* __restrict__ boff,
                        int* __restrict__ row_ptr, int* __restrict__ cursor, int n) {
    __shared__ int s[512];
    int b = blockIdx.x, t = threadIdx.x;
    int i = b * 512 + t;
    int x = (i < n) ? cnt[i] : 0;
    s[t] = x; __syncthreads();
    for (int d = 1; d < 512; d <<= 1) {
        int v = (t >= d) ? s[t - d] : 0;
        __syncthreads();
        s[t] += v;
        __syncthreads();
    }
    int excl = s[t] - x + boff[b];
    if (i < n) { row_ptr[i] = excl; cursor[i] = excl; }
}

// paired scatter: one 8B store per edge (src, weight-bits) -> half the random lines
__global__ void k_scatter(const int* __restrict__ src, const int* __restrict__ dst,
                          const float* __restrict__ w, int* __restrict__ cursor,
                          i32x2* __restrict__ epair, int e) {
    for (int i = blockIdx.x * blockDim.x + threadIdx.x; i < e; i += gridDim.x * blockDim.x) {
        int d = dst[i];
        int p = atomicAdd(&cursor[d], 1);
        i32x2 v; v.x = src[i]; v.y = __float_as_int(w[i]);
        epair[p] = v;
    }
}

// ---------------- W[K][M] fp32 -> split-transposed Wth/Wtl[M][K] fp16 ----------------

__global__ void k_transp_split(const float* __restrict__ W,
                               _Float16* __restrict__ Wth, _Float16* __restrict__ Wtl,
                               int K, int M) {
    __shared__ float tile[32][33];
    int bx = blockIdx.x * 32;  // M dim
    int by = blockIdx.y * 32;  // K dim
    int tx = threadIdx.x, ty = threadIdx.y;
    for (int i = ty; i < 32; i += 8)
        tile[i][tx] = W[(size_t)(by + i) * M + bx + tx];
    __syncthreads();
    for (int i = ty; i < 32; i += 8) {
        float w = tile[tx][i];
        _Float16 h = (_Float16)w;
        _Float16 l = (_Float16)(w - (float)h);
        Wth[(size_t)(bx + i) * K + by + tx] = h;
        Wtl[(size_t)(bx + i) * K + by + tx] = l;
    }
}

// ---------------- split fp16 MFMA GEMM (fp32 A): C = A @ Bt^T (layer 1) ----------------

template<int BN, typename OutT>
__global__ __launch_bounds__(256, 2) void k_gemm_split(const float* __restrict__ A,
                                                       const _Float16* __restrict__ Bth,
                                                       const _Float16* __restrict__ Btl,
                                                       OutT* __restrict__ C,
                                                       int n, int m) {
    constexpr int NI  = BN / 32;
    constexpr int BIT = BN / 32;
    __shared__ _Float16 Ash[128 * 64];
    __shared__ _Float16 Asl[128 * 64];
    __shared__ _Float16 Bsh[BN * 64];
    __shared__ _Float16 Bsl[BN * 64];
    int tid = threadIdx.x;
    int wv = tid >> 6, lane = tid & 63;
    int wr = wv >> 1, wc = wv & 1;
    int r0 = blockIdx.y * 128;
    int c0 = blockIdx.x * BN;

    float4 areg[8];
    f16x8 bregh[BIT], bregl[BIT];
    f32x4 acc[4][NI];
    #pragma unroll
    for (int i = 0; i < 4; i++)
        #pragma unroll
        for (int j = 0; j < NI; j++)
            acc[i][j] = (f32x4){0.f, 0.f, 0.f, 0.f};

    auto aload = [&](int kt) {
        #pragma unroll
        for (int i = 0; i < 8; ++i) {
            int q = tid + 256 * i;
            int row = q >> 4, c4 = q & 15;
            int gr = r0 + row; if (gr >= n) gr = n - 1;
            areg[i] = *(const float4*)(A + (size_t)gr * 512 + kt * 64 + c4 * 4);
        }
        #pragma unroll
        for (int i = 0; i < BIT; ++i) {
            int q = tid + 256 * i;
            int col = q >> 3, c = q & 7;
            size_t off = (size_t)(c0 + col) * 512 + kt * 64 + c * 8;
            bregh[i] = *(const f16x8*)(Bth + off);
            bregl[i] = *(const f16x8*)(Btl + off);
        }
    };

    aload(0);
    for (int kt = 0; kt < 8; ++kt) {
        __syncthreads();
        #pragma unroll
        for (int i = 0; i < 8; ++i) {
            int q = tid + 256 * i;
            int row = q >> 4, c4 = q & 15;
            int g = c4 ^ ((row & 7) << 1);
            float4 a = areg[i];
            _Float16 hx = (_Float16)a.x, hy = (_Float16)a.y;
            _Float16 hz = (_Float16)a.z, hw = (_Float16)a.w;
            f16x4 h = { hx, hy, hz, hw };
            f16x4 l = { (_Float16)(a.x - (float)hx), (_Float16)(a.y - (float)hy),
                        (_Float16)(a.z - (float)hz), (_Float16)(a.w - (float)hw) };
            *(f16x4*)&Ash[row * 64 + g * 4] = h;
            *(f16x4*)&Asl[row * 64 + g * 4] = l;
        }
        #pragma unroll
        for (int i = 0; i < BIT; ++i) {
            int q = tid + 256 * i;
            int col = q >> 3, c = q & 7;
            int idx = col * 64 + ((c ^ (col & 7)) * 8);
            *(f16x8*)&Bsh[idx] = bregh[i];
            *(f16x8*)&Bsl[idx] = bregl[i];
        }
        __syncthreads();
        if (kt < 7) aload(kt + 1);
        #pragma unroll
        for (int ks = 0; ks < 2; ++ks) {
            f16x8 afh[4], afl[4], bfh[NI], bfl[NI];
            int cch = ks * 4 + (lane >> 4);
            #pragma unroll
            for (int mi = 0; mi < 4; ++mi) {
                int row = wr * 64 + mi * 16 + (lane & 15);
                int idx = row * 64 + (((cch * 2) ^ ((row & 7) << 1)) * 4);
                afh[mi] = *(const f16x8*)&Ash[idx];
                afl[mi] = *(const f16x8*)&Asl[idx];
            }
            #pragma unroll
            for (int ni = 0; ni < NI; ++ni) {
                int col = wc * (BN / 2) + ni * 16 + (lane & 15);
                int idx = col * 64 + ((cch ^ (col & 7)) * 8);
                bfh[ni] = *(const f16x8*)&Bsh[idx];
                bfl[ni] = *(const f16x8*)&Bsl[idx];
            }
            #pragma unroll
            for (int mi = 0; mi < 4; ++mi)
                #pragma unroll
                for (int ni = 0; ni < NI; ++ni) {
                    acc[mi][ni] = __builtin_amdgcn_mfma_f32_16x16x32_f16(
                        afh[mi], bfl[ni], acc[mi][ni], 0, 0, 0);
                    acc[mi][ni] = __builtin_amdgcn_mfma_f32_16x16x32_f16(
                        afl[mi], bfh[ni], acc[mi][ni], 0, 0, 0);
                    acc[mi][ni] = __builtin_amdgcn_mfma_f32_16x16x32_f16(
                        afh[mi], bfh[ni], acc[mi][ni], 0, 0, 0);
                }
        }
    }

    #pragma unroll
    for (int mi = 0; mi < 4; ++mi) {
        #pragma unroll
        for (int j = 0; j < 4; ++j) {
            int gr = r0 + wr * 64 + mi * 16 + (lane >> 4) * 4 + j;
            if (gr < n) {
                #pragma unroll
                for (int ni = 0; ni < NI; ++ni) {
                    int gc = c0 + wc * (BN / 2) + ni * 16 + (lane & 15);
                    C[(size_t)gr * m + gc] = (OutT)acc[mi][ni][j];
                }
            }
        }
    }
}

// ---------------- fp16-A, split-W MFMA GEMM (layers 2,3), 3 blocks/CU ----------------

template<int BN, typename OutT>
__global__ __launch_bounds__(256, 3) void k_gemm_f16w2(const _Float16* __restrict__ A,
                                                       const _Float16* __restrict__ Bth,
                                                       const _Float16* __restrict__ Btl,
                                                       OutT* __restrict__ C,
                                                       int n, int m) {
    constexpr int NI  = BN / 32;
    constexpr int BIT = BN / 32;
    __shared__ _Float16 As[128 * 64];
    __shared__ _Float16 Bsh[BN * 64];
    __shared__ _Float16 Bsl[BN * 64];
    int tid = threadIdx.x;
    int wv = tid >> 6, lane = tid & 63;
    int wr = wv >> 1, wc = wv & 1;
    int r0 = blockIdx.y * 128;
    int c0 = blockIdx.x * BN;

    f16x8 areg[4], bregh[BIT], bregl[BIT];
    f32x4 acc[4][NI];
    #pragma unroll
    for (int i = 0; i < 4; i++)
        #pragma unroll
        for (int j = 0; j < NI; j++)
            acc[i][j] = (f32x4){0.f, 0.f, 0.f, 0.f};

    auto aload = [&](int kt) {
        #pragma unroll
        for (int i = 0; i < 4; ++i) {
            int q = tid + 256 * i;
            int row = q >> 3, c = q & 7;
            int gr = r0 + row; if (gr >= n) gr = n - 1;
            areg[i] = *(const f16x8*)(A + (size_t)gr * 512 + kt * 64 + c * 8);
        }
        #pragma unroll
        for (int i = 0; i < BIT; ++i) {
            int q = tid + 256 * i;
            int col = q >> 3, c = q & 7;
            size_t off = (size_t)(c0 + col) * 512 + kt * 64 + c * 8;
            bregh[i] = *(const f16x8*)(Bth + off);
            bregl[i] = *(const f16x8*)(Btl + off);
        }
    };

    aload(0);
    for (int kt = 0; kt < 8; ++kt) {
        __syncthreads();
        #pragma unroll
        for (int i = 0; i < 4; ++i) {
            int q = tid + 256 * i;
            int row = q >> 3, c = q & 7;
            *(f16x8*)&As[row * 64 + ((c ^ (row & 7)) * 8)] = areg[i];
        }
        #pragma unroll
        for (int i = 0; i < BIT; ++i) {
            int q = tid + 256 * i;
            int col = q >> 3, c = q & 7;
            int idx = col * 64 + ((c ^ (col & 7)) * 8);
            *(f16x8*)&Bsh[idx] = bregh[i];
            *(f16x8*)&Bsl[idx] = bregl[i];
        }
        __syncthreads();
        if (kt < 7) aload(kt + 1);
        #pragma unroll
        for (int ks = 0; ks < 2; ++ks) {
            f16x8 af[4], bfh[NI], bfl[NI];
            int cch = ks * 4 + (lane >> 4);
            #pragma unroll
            for (int mi = 0; mi < 4; ++mi) {
                int row = wr * 64 + mi * 16 + (lane & 15);
                af[mi] = *(const f16x8*)&As[row * 64 + ((cch ^ (row & 7)) * 8)];
            }
            #pragma unroll
            for (int ni = 0; ni < NI; ++ni) {
                int col = wc * (BN / 2) + ni * 16 + (lane & 15);
                int idx = col * 64 + ((cch ^ (col & 7)) * 8);
                bfh[ni] = *(const f16x8*)&Bsh[idx];
                bfl[ni] = *(const f16x8*)&Bsl[idx];
            }
            #pragma unroll
            for (int mi = 0; mi < 4; ++mi)
                #pragma unroll
                for (int ni = 0; ni < NI; ++ni) {
                    acc[mi][ni] = __builtin_amdgcn_mfma_f32_16x16x32_f16(
                        af[mi], bfl[ni], acc[mi][ni], 0, 0, 0);
                    acc[mi][ni] = __builtin_amdgcn_mfma_f32_16x16x32_f16(
                        af[mi], bfh[ni], acc[mi][ni], 0, 0, 0);
                }
        }
    }

    #pragma unroll
    for (int mi = 0; mi < 4; ++mi) {
        #pragma unroll
        for (int j = 0; j < 4; ++j) {
            int gr = r0 + wr * 64 + mi * 16 + (lane >> 4) * 4 + j;
            if (gr < n) {
                #pragma unroll
                for (int ni = 0; ni < NI; ++ni) {
                    int gc = c0 + wc * (BN / 2) + ni * 16 + (lane & 15);
                    C[(size_t)gr * m + gc] = (OutT)acc[mi][ni][j];
                }
            }
        }
    }
}

// ---------------- SpMM K=512: fp16 gather -> fp16 out (+bias, +relu), ILP 8 ----------------

__global__ __launch_bounds__(64) void k_spmm512_h2h(const int* __restrict__ rowp,
                                                    const i32x2* __restrict__ epair,
                                                    const _Float16* __restrict__ H,
                                                    const float* __restrict__ bias,
                                                    _Float16* __restrict__ out,
                                                    int relu) {
    int row = blockIdx.x;
    int t = threadIdx.x;                 // 64 threads, each owns 8 cols (f16x8)
    int s0 = rowp[row], s1 = rowp[row + 1];
    const f16x8* H8 = (const f16x8*)H;   // row stride 64 vectors
    float a0 = 0.f, a1 = 0.f, a2 = 0.f, a3 = 0.f;
    float a4 = 0.f, a5 = 0.f, a6 = 0.f, a7 = 0.f;
    __shared__ i32x2 le[64];
    for (int base = s0; base < s1; base += 64) {
        int nn = s1 - base; if (nn > 64) nn = 64;
        __syncthreads();
        if (t < nn) le[t] = __builtin_nontemporal_load(epair + base + t);
        __syncthreads();
        int e = 0;
        for (; e + 8 <= nn; e += 8) {      // 8 outstanding 1KB wave-gathers
            i32x2 p0 = le[e],     p1 = le[e + 1], p2 = le[e + 2], p3 = le[e + 3];
            i32x2 p4 = le[e + 4], p5 = le[e + 5], p6 = le[e + 6], p7 = le[e + 7];
            f16x8 h0 = H8[(size_t)p0.x * 64 + t];
            f16x8 h1 = H8[(size_t)p1.x * 64 + t];
            f16x8 h2 = H8[(size_t)p2.x * 64 + t];
            f16x8 h3 = H8[(size_t)p3.x * 64 + t];
            f16x8 h4 = H8[(size_t)p4.x * 64 + t];
            f16x8 h5 = H8[(size_t)p5.x * 64 + t];
            f16x8 h6 = H8[(size_t)p6.x * 64 + t];
            f16x8 h7 = H8[(size_t)p7.x * 64 + t];
            float w0 = __int_as_float(p0.y), w1 = __int_as_float(p1.y);
            float w2 = __int_as_float(p2.y), w3 = __int_as_float(p3.y);
            float w4 = __int_as_float(p4.y), w5 = __int_as_float(p5.y);
            float w6 = __int_as_float(p6.y), w7 = __int_as_float(p7.y);
            a0 += w0*(float)h0[0] + w1*(float)h1[0] + w2*(float)h2[0] + w3*(float)h3[0]
                + w4*(float)h4[0] + w5*(float)h5[0] + w6*(float)h6[0] + w7*(float)h7[0];
            a1 += w0*(float)h0[1] + w1*(float)h1[1] + w2*(float)h2[1] + w3*(float)h3[1]
                + w4*(float)h4[1] + w5*(float)h5[1] + w6*(float)h6[1] + w7*(float)h7[1];
            a2 += w0*(float)h0[2] + w1*(float)h1[2] + w2*(float)h2[2] + w3*(float)h3[2]
                + w4*(float)h4[2] + w5*(float)h5[2] + w6*(float)h6[2] + w7*(float)h7[2];
            a3 += w0*(float)h0[3] + w1*(float)h1[3] + w2*(float)h2[3] + w3*(float)h3[3]
                + w4*(float)h4[3] + w5*(float)h5[3] + w6*(float)h6[3] + w7*(float)h7[3];
            a4 += w0*(float)h0[4] + w1*(float)h1[4] + w2*(float)h2[4] + w3*(float)h3[4]
                + w4*(float)h4[4] + w5*(float)h5[4] + w6*(float)h6[4] + w7*(float)h7[4];
            a5 += w0*(float)h0[5] + w1*(float)h1[5] + w2*(float)h2[5] + w3*(float)h3[5]
                + w4*(float)h4[5] + w5*(float)h5[5] + w6*(float)h6[5] + w7*(float)h7[5];
            a6 += w0*(float)h0[6] + w1*(float)h1[6] + w2*(float)h2[6] + w3*(float)h3[6]
                + w4*(float)h4[6] + w5*(float)h5[6] + w6*(float)h6[6] + w7*(float)h7[6];
            a7 += w0*(float)h0[7] + w1*(float)h1[7] + w2*(float)h2[7] + w3*(float)h3[7]
                + w4*(float)h4[7] + w5*(float)h5[7] + w6*(float)h6[7] + w7*(float)h7[7];
        }
        for (; e < nn; ++e) {
            i32x2 pe = le[e];
            f16x8 h = H8[(size_t)pe.x * 64 + t]; float w = __int_as_float(pe.y);
            a0 += w * (float)h[0]; a1 += w * (float)h[1];
            a2 += w * (float)h[2]; a3 += w * (float)h[3];
            a4 += w * (float)h[4]; a5 += w * (float)h[5];
            a6 += w * (float)h[6]; a7 += w * (float)h[7];
        }
    }
    const float4* b4 = (const float4*)bias;
    float4 blo = b4[t * 2], bhi = b4[t * 2 + 1];
    a0 += blo.x; a1 += blo.y; a2 += blo.z; a3 += blo.w;
    a4 += bhi.x; a5 += bhi.y; a6 += bhi.z; a7 += bhi.w;
    if (relu) {
        a0 = fmaxf(a0, 0.f); a1 = fmaxf(a1, 0.f); a2 = fmaxf(a2, 0.f); a3 = fmaxf(a3, 0.f);
        a4 = fmaxf(a4, 0.f); a5 = fmaxf(a5, 0.f); a6 = fmaxf(a6, 0.f); a7 = fmaxf(a7, 0.f);
    }
    f16x8 o = { (_Float16)a0, (_Float16)a1, (_Float16)a2, (_Float16)a3,
                (_Float16)a4, (_Float16)a5, (_Float16)a6, (_Float16)a7 };
    ((f16x8*)out)[(size_t)row * 64 + t] = o;
}

// ---------------- SpMM K=64 fp32 + bias + softmax, one wave per dst row ----------------

__global__ __launch_bounds__(256) void k_spmm64_softmax(const int* __restrict__ rowp,
                                                        const i32x2* __restrict__ epair,
                                                        const float* __restrict__ H,
                                                        const float* __restrict__ bias,
                                                        float* __restrict__ out, int n) {
    int wid  = threadIdx.x >> 6;
    int lane = threadIdx.x & 63;
    int row  = blockIdx.x * 4 + wid;
    if (row >= n) return;
    int s0 = rowp[row], s1 = rowp[row + 1];
    float acc = 0.f;
    int e = s0;
    for (; e + 4 <= s1; e += 4) {
        i32x2 p0 = epair[e],     p1 = epair[e + 1];
        i32x2 p2 = epair[e + 2], p3 = epair[e + 3];
        float h0 = H[(size_t)p0.x * 64 + lane];
        float h1 = H[(size_t)p1.x * 64 + lane];
        float h2 = H[(size_t)p2.x * 64 + lane];
        float h3 = H[(size_t)p3.x * 64 + lane];
        acc += __int_as_float(p0.y) * h0 + __int_as_float(p1.y) * h1
             + __int_as_float(p2.y) * h2 + __int_as_float(p3.y) * h3;
    }
    for (; e < s1; ++e) {
        i32x2 pe = epair[e];
        acc += __int_as_float(pe.y) * H[(size_t)pe.x * 64 + lane];
    }
    acc += bias[lane];
    float m = acc;
    for (int d = 32; d > 0; d >>= 1) m = fmaxf(m, __shfl_xor(m, d));
    float p = __expf(acc - m);
    float s = p;
    for (int d = 32; d > 0; d >>= 1) s += __shfl_xor(s, d);
    __builtin_nontemporal_store(p / s, out + (size_t)row * 64 + lane);
}

// ---------------- launch ----------------

extern "C" void kernel_launch(void* const* d_in, const int* in_sizes, int n_in,
                              void* d_out, int out_size, void* d_ws, size_t ws_size,
                              hipStream_t stream) {
    const float* X    = (const float*)d_in[0];
    const int*   esrc = (const int*)d_in[1];
    const int*   edst = (const int*)d_in[2];
    const float* ewin = (const float*)d_in[3];
    const float* W0   = (const float*)d_in[4];
    const float* b0   = (const float*)d_in[5];
    const float* W1   = (const float*)d_in[6];
    const float* b1   = (const float*)d_in[7];
    const float* W2   = (const float*)d_in[8];
    const float* b2   = (const float*)d_in[9];
    float* out = (float*)d_out;

    const int N = GN;
    const int E = GE;

    uint8_t* p = (uint8_t*)d_ws;
    auto alloc = [&](size_t bytes) -> void* {
        void* r = (void*)p;
        p += (bytes + 255) & ~(size_t)255;
        return r;
    };
    _Float16* bufM  = (_Float16*)alloc((size_t)N * 512 * 2);   // GEMM out (fp16, gather table)
    _Float16* bufG  = (_Float16*)alloc((size_t)N * 512 * 2);   // spmm out H (fp16, next A)
    float*    bufC3 = (float*)alloc((size_t)N * 64 * 4);       // layer-3 logits (fp32)
    _Float16* W0th  = (_Float16*)alloc((size_t)512 * 512 * 2);
    _Float16* W0tl  = (_Float16*)alloc((size_t)512 * 512 * 2);
    _Float16* W1th  = (_Float16*)alloc((size_t)512 * 512 * 2);
    _Float16* W1tl  = (_Float16*)alloc((size_t)512 * 512 * 2);
    _Float16* W2th  = (_Float16*)alloc((size_t)64 * 512 * 2);
    _Float16* W2tl  = (_Float16*)alloc((size_t)64 * 512 * 2);
    int*   cnt     = (int*)alloc((size_t)N * 4);
    int*   row_ptr = (int*)alloc((size_t)(N + 1) * 4);
    int*   cursor  = (int*)alloc((size_t)N * 4);
    i32x2* epair   = (i32x2*)alloc((size_t)E * 8);
    int*   bsum    = (int*)alloc(1024 * 4);
    int*   boff    = (int*)alloc(1024 * 4);

    // CSR by dst (paired edges)
    int nch = (N + 511) / 512;
    k_zero<<<(N + 255) / 256, 256, 0, stream>>>(cnt, N);
    k_hist<<<2048, 256, 0, stream>>>(edst, cnt, E);
    k_chunksum<<<nch, 256, 0, stream>>>(cnt, bsum, N);
    k_scanb<<<1, 64, 0, stream>>>(bsum, boff, nch, row_ptr, N);
    k_scanw<<<nch, 512, 0, stream>>>(cnt, boff, row_ptr, cursor, N);
    k_scatter<<<2048, 256, 0, stream>>>(esrc, edst, ewin, cursor, epair, E);

    // weight split-transpose (hi/lo fp16)
    k_transp_split<<<dim3(16, 16), dim3(32, 8), 0, stream>>>(W0, W0th, W0tl, 512, 512);
    k_transp_split<<<dim3(16, 16), dim3(32, 8), 0, stream>>>(W1, W1th, W1tl, 512, 512);
    k_transp_split<<<dim3(2, 16),  dim3(32, 8), 0, stream>>>(W2, W2th, W2tl, 512, 64);

    int gy = (N + 127) / 128;
    // layer 1: M = X @ W0 (fp32-A split, X never rounded)
    k_gemm_split<128, _Float16><<<dim3(4, gy), 256, 0, stream>>>(X, W0th, W0tl, bufM, N, 512);
    k_spmm512_h2h<<<N, 64, 0, stream>>>(row_ptr, epair, bufM, b0, bufG, 1);
    // layer 2
    k_gemm_f16w2<128, _Float16><<<dim3(4, gy), 256, 0, stream>>>(bufG, W1th, W1tl, bufM, N, 512);
    k_spmm512_h2h<<<N, 64, 0, stream>>>(row_ptr, epair, bufM, b1, bufG, 1);
    // layer 3 + softmax (fp32 logits)
    k_gemm_f16w2<64, float><<<dim3(1, gy), 256, 0, stream>>>(bufG, W2th, W2tl, bufC3, N, 64);
    k_spmm64_softmax<<<(N + 3) / 4, 256, 0, stream>>>(row_ptr, epair, bufC3, b2, out, N);
}

// Round 12
// 1657.937 us; speedup vs baseline: 1.0367x; 1.0367x over previous
//
#include <hip/hip_runtime.h>
#include <hip/hip_bf16.h>
#include <cstdint>
#include <cstddef>

#define GN 100000
#define GE 3200000

typedef __attribute__((ext_vector_type(8))) _Float16 f16x8;
typedef __attribute__((ext_vector_type(4))) _Float16 f16x4;
typedef __attribute__((ext_vector_type(4))) float f32x4;
typedef __attribute__((ext_vector_type(2))) int i32x2;   // NT-safe 8B edge pair

// ---------------- CSR build ----------------

__global__ void k_zero(int* __restrict__ p, int n) {
    int i = blockIdx.x * blockDim.x + threadIdx.x;
    if (i < n) p[i] = 0;
}

__global__ void k_hist(const int* __restrict__ dst, int* __restrict__ cnt, int e) {
    for (int i = blockIdx.x * blockDim.x + threadIdx.x; i < e; i += gridDim.x * blockDim.x)
        atomicAdd(&cnt[__builtin_nontemporal_load(dst + i)], 1);
}

__global__ void k_chunksum(const int* __restrict__ cnt, int* __restrict__ bsum, int n) {
    __shared__ int s[256];
    int b = blockIdx.x, t = threadIdx.x;
    int i0 = b * 512;
    int v = 0;
    int i1 = i0 + t;        if (i1 < n) v += cnt[i1];
    int i2 = i0 + 256 + t;  if (i2 < n) v += cnt[i2];
    s[t] = v; __syncthreads();
    for (int d = 128; d > 0; d >>= 1) {
        if (t < d) s[t] += s[t + d];
        __syncthreads();
    }
    if (t == 0) bsum[b] = s[0];
}

__global__ void k_scanb(const int* __restrict__ bsum, int* __restrict__ boff, int nb,
                        int* __restrict__ row_ptr, int n) {
    if (threadIdx.x == 0 && blockIdx.x == 0) {
        int acc = 0;
        for (int b = 0; b < nb; b++) { boff[b] = acc; acc += bsum[b]; }
        row_ptr[n] = acc;
    }
}

__global__ void k_scanw(const int* __restrict__ cnt, const int* __restrict__ boff,
                        int* __restrict__ row_ptr, int* __restrict__ cursor, int n) {
    __shared__ int s[512];
    int b = blockIdx.x, t = threadIdx.x;
    int i = b * 512 + t;
    int x = (i < n) ? cnt[i] : 0;
    s[t] = x; __syncthreads();
    for (int d = 1; d < 512; d <<= 1) {
        int v = (t >= d) ? s[t - d] : 0;
        __syncthreads();
        s[t] += v;
        __syncthreads();
    }
    int excl = s[t] - x + boff[b];
    if (i < n) { row_ptr[i] = excl; cursor[i] = excl; }
}

// paired scatter: one 8B store per edge (src, weight-bits)
__global__ void k_scatter(const int* __restrict__ src, const int* __restrict__ dst,
                          const float* __restrict__ w, int* __restrict__ cursor,
                          i32x2* __restrict__ epair, int e) {
    for (int i = blockIdx.x * blockDim.x + threadIdx.x; i < e; i += gridDim.x * blockDim.x) {
        int d = __builtin_nontemporal_load(dst + i);
        int p = atomicAdd(&cursor[d], 1);
        i32x2 v;
        v.x = __builtin_nontemporal_load(src + i);
        v.y = __float_as_int(__builtin_nontemporal_load(w + i));
        epair[p] = v;
    }
}

// ---------------- W[K][M] fp32 -> split-transposed Wth/Wtl[M][K] fp16 ----------------

__global__ void k_transp_split(const float* __restrict__ W,
                               _Float16* __restrict__ Wth, _Float16* __restrict__ Wtl,
                               int K, int M) {
    __shared__ float tile[32][33];
    int bx = blockIdx.x * 32;  // M dim
    int by = blockIdx.y * 32;  // K dim
    int tx = threadIdx.x, ty = threadIdx.y;
    for (int i = ty; i < 32; i += 8)
        tile[i][tx] = W[(size_t)(by + i) * M + bx + tx];
    __syncthreads();
    for (int i = ty; i < 32; i += 8) {
        float w = tile[tx][i];
        _Float16 h = (_Float16)w;
        _Float16 l = (_Float16)(w - (float)h);
        Wth[(size_t)(bx + i) * K + by + tx] = h;
        Wtl[(size_t)(bx + i) * K + by + tx] = l;
    }
}

// ---------------- split fp16 MFMA GEMM (fp32 A, split W): layer 1 ----------------
// acc = Ah*Bh + Al*Bh + Ah*Bl — X and W0 both effectively ~22-bit.

template<int BN, typename OutT>
__global__ __launch_bounds__(256, 2) void k_gemm_split(const float* __restrict__ A,
                                                       const _Float16* __restrict__ Bth,
                                                       const _Float16* __restrict__ Btl,
                                                       OutT* __restrict__ C,
                                                       int n, int m) {
    constexpr int NI  = BN / 32;
    constexpr int BIT = BN / 32;
    __shared__ _Float16 Ash[128 * 64];
    __shared__ _Float16 Asl[128 * 64];
    __shared__ _Float16 Bsh[BN * 64];
    __shared__ _Float16 Bsl[BN * 64];
    int tid = threadIdx.x;
    int wv = tid >> 6, lane = tid & 63;
    int wr = wv >> 1, wc = wv & 1;
    int r0 = blockIdx.y * 128;
    int c0 = blockIdx.x * BN;

    float4 areg[8];
    f16x8 bregh[BIT], bregl[BIT];
    f32x4 acc[4][NI];
    #pragma unroll
    for (int i = 0; i < 4; i++)
        #pragma unroll
        for (int j = 0; j < NI; j++)
            acc[i][j] = (f32x4){0.f, 0.f, 0.f, 0.f};

    auto aload = [&](int kt) {
        #pragma unroll
        for (int i = 0; i < 8; ++i) {
            int q = tid + 256 * i;
            int row = q >> 4, c4 = q & 15;
            int gr = r0 + row; if (gr >= n) gr = n - 1;
            areg[i] = *(const float4*)(A + (size_t)gr * 512 + kt * 64 + c4 * 4);
        }
        #pragma unroll
        for (int i = 0; i < BIT; ++i) {
            int q = tid + 256 * i;
            int col = q >> 3, c = q & 7;
            size_t off = (size_t)(c0 + col) * 512 + kt * 64 + c * 8;
            bregh[i] = *(const f16x8*)(Bth + off);
            bregl[i] = *(const f16x8*)(Btl + off);
        }
    };

    aload(0);
    for (int kt = 0; kt < 8; ++kt) {
        __syncthreads();
        #pragma unroll
        for (int i = 0; i < 8; ++i) {
            int q = tid + 256 * i;
            int row = q >> 4, c4 = q & 15;
            int g = c4 ^ ((row & 7) << 1);
            float4 a = areg[i];
            _Float16 hx = (_Float16)a.x, hy = (_Float16)a.y;
            _Float16 hz = (_Float16)a.z, hw = (_Float16)a.w;
            f16x4 h = { hx, hy, hz, hw };
            f16x4 l = { (_Float16)(a.x - (float)hx), (_Float16)(a.y - (float)hy),
                        (_Float16)(a.z - (float)hz), (_Float16)(a.w - (float)hw) };
            *(f16x4*)&Ash[row * 64 + g * 4] = h;
            *(f16x4*)&Asl[row * 64 + g * 4] = l;
        }
        #pragma unroll
        for (int i = 0; i < BIT; ++i) {
            int q = tid + 256 * i;
            int col = q >> 3, c = q & 7;
            int idx = col * 64 + ((c ^ (col & 7)) * 8);
            *(f16x8*)&Bsh[idx] = bregh[i];
            *(f16x8*)&Bsl[idx] = bregl[i];
        }
        __syncthreads();
        if (kt < 7) aload(kt + 1);
        #pragma unroll
        for (int ks = 0; ks < 2; ++ks) {
            f16x8 afh[4], afl[4], bfh[NI], bfl[NI];
            int cch = ks * 4 + (lane >> 4);
            #pragma unroll
            for (int mi = 0; mi < 4; ++mi) {
                int row = wr * 64 + mi * 16 + (lane & 15);
                int idx = row * 64 + (((cch * 2) ^ ((row & 7) << 1)) * 4);
                afh[mi] = *(const f16x8*)&Ash[idx];
                afl[mi] = *(const f16x8*)&Asl[idx];
            }
            #pragma unroll
            for (int ni = 0; ni < NI; ++ni) {
                int col = wc * (BN / 2) + ni * 16 + (lane & 15);
                int idx = col * 64 + ((cch ^ (col & 7)) * 8);
                bfh[ni] = *(const f16x8*)&Bsh[idx];
                bfl[ni] = *(const f16x8*)&Bsl[idx];
            }
            #pragma unroll
            for (int mi = 0; mi < 4; ++mi)
                #pragma unroll
                for (int ni = 0; ni < NI; ++ni) {
                    acc[mi][ni] = __builtin_amdgcn_mfma_f32_16x16x32_f16(
                        afh[mi], bfl[ni], acc[mi][ni], 0, 0, 0);
                    acc[mi][ni] = __builtin_amdgcn_mfma_f32_16x16x32_f16(
                        afl[mi], bfh[ni], acc[mi][ni], 0, 0, 0);
                    acc[mi][ni] = __builtin_amdgcn_mfma_f32_16x16x32_f16(
                        afh[mi], bfh[ni], acc[mi][ni], 0, 0, 0);
                }
        }
    }

    #pragma unroll
    for (int mi = 0; mi < 4; ++mi) {
        #pragma unroll
        for (int j = 0; j < 4; ++j) {
            int gr = r0 + wr * 64 + mi * 16 + (lane >> 4) * 4 + j;
            if (gr < n) {
                #pragma unroll
                for (int ni = 0; ni < NI; ++ni) {
                    int gc = c0 + wc * (BN / 2) + ni * 16 + (lane & 15);
                    C[(size_t)gr * m + gc] = (OutT)acc[mi][ni][j];
                }
            }
        }
    }
}

// ---------------- fp16-A, split-W MFMA GEMM (layers 2,3): 2 MFMA/pair, (256,2) ----------------

template<int BN, typename OutT>
__global__ __launch_bounds__(256, 2) void k_gemm_f16w2(const _Float16* __restrict__ A,
                                                       const _Float16* __restrict__ Bth,
                                                       const _Float16* __restrict__ Btl,
                                                       OutT* __restrict__ C,
                                                       int n, int m) {
    constexpr int NI  = BN / 32;
    constexpr int BIT = BN / 32;
    __shared__ _Float16 As[128 * 64];
    __shared__ _Float16 Bsh[BN * 64];
    __shared__ _Float16 Bsl[BN * 64];
    int tid = threadIdx.x;
    int wv = tid >> 6, lane = tid & 63;
    int wr = wv >> 1, wc = wv & 1;
    int r0 = blockIdx.y * 128;
    int c0 = blockIdx.x * BN;

    f16x8 areg[4], bregh[BIT], bregl[BIT];
    f32x4 acc[4][NI];
    #pragma unroll
    for (int i = 0; i < 4; i++)
        #pragma unroll
        for (int j = 0; j < NI; j++)
            acc[i][j] = (f32x4){0.f, 0.f, 0.f, 0.f};

    auto aload = [&](int kt) {
        #pragma unroll
        for (int i = 0; i < 4; ++i) {
            int q = tid + 256 * i;
            int row = q >> 3, c = q & 7;
            int gr = r0 + row; if (gr >= n) gr = n - 1;
            areg[i] = *(const f16x8*)(A + (size_t)gr * 512 + kt * 64 + c * 8);
        }
        #pragma unroll
        for (int i = 0; i < BIT; ++i) {
            int q = tid + 256 * i;
            int col = q >> 3, c = q & 7;
            size_t off = (size_t)(c0 + col) * 512 + kt * 64 + c * 8;
            bregh[i] = *(const f16x8*)(Bth + off);
            bregl[i] = *(const f16x8*)(Btl + off);
        }
    };

    aload(0);
    for (int kt = 0; kt < 8; ++kt) {
        __syncthreads();
        #pragma unroll
        for (int i = 0; i < 4; ++i) {
            int q = tid + 256 * i;
            int row = q >> 3, c = q & 7;
            *(f16x8*)&As[row * 64 + ((c ^ (row & 7)) * 8)] = areg[i];
        }
        #pragma unroll
        for (int i = 0; i < BIT; ++i) {
            int q = tid + 256 * i;
            int col = q >> 3, c = q & 7;
            int idx = col * 64 + ((c ^ (col & 7)) * 8);
            *(f16x8*)&Bsh[idx] = bregh[i];
            *(f16x8*)&Bsl[idx] = bregl[i];
        }
        __syncthreads();
        if (kt < 7) aload(kt + 1);
        #pragma unroll
        for (int ks = 0; ks < 2; ++ks) {
            f16x8 af[4], bfh[NI], bfl[NI];
            int cch = ks * 4 + (lane >> 4);
            #pragma unroll
            for (int mi = 0; mi < 4; ++mi) {
                int row = wr * 64 + mi * 16 + (lane & 15);
                af[mi] = *(const f16x8*)&As[row * 64 + ((cch ^ (row & 7)) * 8)];
            }
            #pragma unroll
            for (int ni = 0; ni < NI; ++ni) {
                int col = wc * (BN / 2) + ni * 16 + (lane & 15);
                int idx = col * 64 + ((cch ^ (col & 7)) * 8);
                bfh[ni] = *(const f16x8*)&Bsh[idx];
                bfl[ni] = *(const f16x8*)&Bsl[idx];
            }
            #pragma unroll
            for (int mi = 0; mi < 4; ++mi)
                #pragma unroll
                for (int ni = 0; ni < NI; ++ni) {
                    acc[mi][ni] = __builtin_amdgcn_mfma_f32_16x16x32_f16(
                        af[mi], bfl[ni], acc[mi][ni], 0, 0, 0);
                    acc[mi][ni] = __builtin_amdgcn_mfma_f32_16x16x32_f16(
                        af[mi], bfh[ni], acc[mi][ni], 0, 0, 0);
                }
        }
    }

    #pragma unroll
    for (int mi = 0; mi < 4; ++mi) {
        #pragma unroll
        for (int j = 0; j < 4; ++j) {
            int gr = r0 + wr * 64 + mi * 16 + (lane >> 4) * 4 + j;
            if (gr < n) {
                #pragma unroll
                for (int ni = 0; ni < NI; ++ni) {
                    int gc = c0 + wc * (BN / 2) + ni * 16 + (lane & 15);
                    C[(size_t)gr * m + gc] = (OutT)acc[mi][ni][j];
                }
            }
        }
    }
}

// ---------------- SpMM K=512: fp16 gather -> fp16 out (+bias, +relu), ILP 8 ----------------

__global__ __launch_bounds__(64) void k_spmm512_h2h(const int* __restrict__ rowp,
                                                    const i32x2* __restrict__ epair,
                                                    const _Float16* __restrict__ H,
                                                    const float* __restrict__ bias,
                                                    _Float16* __restrict__ out,
                                                    int relu) {
    int row = blockIdx.x;
    int t = threadIdx.x;                 // 64 threads, each owns 8 cols (f16x8)
    int s0 = rowp[row], s1 = rowp[row + 1];
    const f16x8* H8 = (const f16x8*)H;   // row stride 64 vectors
    float a0 = 0.f, a1 = 0.f, a2 = 0.f, a3 = 0.f;
    float a4 = 0.f, a5 = 0.f, a6 = 0.f, a7 = 0.f;
    __shared__ i32x2 le[64];
    for (int base = s0; base < s1; base += 64) {
        int nn = s1 - base; if (nn > 64) nn = 64;
        __syncthreads();
        if (t < nn) le[t] = __builtin_nontemporal_load(epair + base + t);
        __syncthreads();
        int e = 0;
        for (; e + 8 <= nn; e += 8) {      // 8 outstanding 1KB wave-gathers
            i32x2 p0 = le[e],     p1 = le[e + 1], p2 = le[e + 2], p3 = le[e + 3];
            i32x2 p4 = le[e + 4], p5 = le[e + 5], p6 = le[e + 6], p7 = le[e + 7];
            f16x8 h0 = H8[(size_t)p0.x * 64 + t];
            f16x8 h1 = H8[(size_t)p1.x * 64 + t];
            f16x8 h2 = H8[(size_t)p2.x * 64 + t];
            f16x8 h3 = H8[(size_t)p3.x * 64 + t];
            f16x8 h4 = H8[(size_t)p4.x * 64 + t];
            f16x8 h5 = H8[(size_t)p5.x * 64 + t];
            f16x8 h6 = H8[(size_t)p6.x * 64 + t];
            f16x8 h7 = H8[(size_t)p7.x * 64 + t];
            float w0 = __int_as_float(p0.y), w1 = __int_as_float(p1.y);
            float w2 = __int_as_float(p2.y), w3 = __int_as_float(p3.y);
            float w4 = __int_as_float(p4.y), w5 = __int_as_float(p5.y);
            float w6 = __int_as_float(p6.y), w7 = __int_as_float(p7.y);
            a0 += w0*(float)h0[0] + w1*(float)h1[0] + w2*(float)h2[0] + w3*(float)h3[0]
                + w4*(float)h4[0] + w5*(float)h5[0] + w6*(float)h6[0] + w7*(float)h7[0];
            a1 += w0*(float)h0[1] + w1*(float)h1[1] + w2*(float)h2[1] + w3*(float)h3[1]
                + w4*(float)h4[1] + w5*(float)h5[1] + w6*(float)h6[1] + w7*(float)h7[1];
            a2 += w0*(float)h0[2] + w1*(float)h1[2] + w2*(float)h2[2] + w3*(float)h3[2]
                + w4*(float)h4[2] + w5*(float)h5[2] + w6*(float)h6[2] + w7*(float)h7[2];
            a3 += w0*(float)h0[3] + w1*(float)h1[3] + w2*(float)h2[3] + w3*(float)h3[3]
                + w4*(float)h4[3] + w5*(float)h5[3] + w6*(float)h6[3] + w7*(float)h7[3];
            a4 += w0*(float)h0[4] + w1*(float)h1[4] + w2*(float)h2[4] + w3*(float)h3[4]
                + w4*(float)h4[4] + w5*(float)h5[4] + w6*(float)h6[4] + w7*(float)h7[4];
            a5 += w0*(float)h0[5] + w1*(float)h1[5] + w2*(float)h2[5] + w3*(float)h3[5]
                + w4*(float)h4[5] + w5*(float)h5[5] + w6*(float)h6[5] + w7*(float)h7[5];
            a6 += w0*(float)h0[6] + w1*(float)h1[6] + w2*(float)h2[6] + w3*(float)h3[6]
                + w4*(float)h4[6] + w5*(float)h5[6] + w6*(float)h6[6] + w7*(float)h7[6];
            a7 += w0*(float)h0[7] + w1*(float)h1[7] + w2*(float)h2[7] + w3*(float)h3[7]
                + w4*(float)h4[7] + w5*(float)h5[7] + w6*(float)h6[7] + w7*(float)h7[7];
        }
        for (; e < nn; ++e) {
            i32x2 pe = le[e];
            f16x8 h = H8[(size_t)pe.x * 64 + t]; float w = __int_as_float(pe.y);
            a0 += w * (float)h[0]; a1 += w * (float)h[1];
            a2 += w * (float)h[2]; a3 += w * (float)h[3];
            a4 += w * (float)h[4]; a5 += w * (float)h[5];
            a6 += w * (float)h[6]; a7 += w * (float)h[7];
        }
    }
    const float4* b4 = (const float4*)bias;
    float4 blo = b4[t * 2], bhi = b4[t * 2 + 1];
    a0 += blo.x; a1 += blo.y; a2 += blo.z; a3 += blo.w;
    a4 += bhi.x; a5 += bhi.y; a6 += bhi.z; a7 += bhi.w;
    if (relu) {
        a0 = fmaxf(a0, 0.f); a1 = fmaxf(a1, 0.f); a2 = fmaxf(a2, 0.f); a3 = fmaxf(a3, 0.f);
        a4 = fmaxf(a4, 0.f); a5 = fmaxf(a5, 0.f); a6 = fmaxf(a6, 0.f); a7 = fmaxf(a7, 0.f);
    }
    f16x8 o = { (_Float16)a0, (_Float16)a1, (_Float16)a2, (_Float16)a3,
                (_Float16)a4, (_Float16)a5, (_Float16)a6, (_Float16)a7 };
    ((f16x8*)out)[(size_t)row * 64 + t] = o;
}

// ---------------- SpMM K=64 fp32 + bias + softmax, one wave per dst row ----------------

__global__ __launch_bounds__(256) void k_spmm64_softmax(const int* __restrict__ rowp,
                                                        const i32x2* __restrict__ epair,
                                                        const float* __restrict__ H,
                                                        const float* __restrict__ bias,
                                                        float* __restrict__ out, int n) {
    int wid  = threadIdx.x >> 6;
    int lane = threadIdx.x & 63;
    int row  = blockIdx.x * 4 + wid;
    if (row >= n) return;
    int s0 = rowp[row], s1 = rowp[row + 1];
    float acc = 0.f;
    int e = s0;
    for (; e + 4 <= s1; e += 4) {
        i32x2 p0 = epair[e],     p1 = epair[e + 1];
        i32x2 p2 = epair[e + 2], p3 = epair[e + 3];
        float h0 = H[(size_t)p0.x * 64 + lane];
        float h1 = H[(size_t)p1.x * 64 + lane];
        float h2 = H[(size_t)p2.x * 64 + lane];
        float h3 = H[(size_t)p3.x * 64 + lane];
        acc += __int_as_float(p0.y) * h0 + __int_as_float(p1.y) * h1
             + __int_as_float(p2.y) * h2 + __int_as_float(p3.y) * h3;
    }
    for (; e < s1; ++e) {
        i32x2 pe = epair[e];
        acc += __int_as_float(pe.y) * H[(size_t)pe.x * 64 + lane];
    }
    acc += bias[lane];
    float m = acc;
    for (int d = 32; d > 0; d >>= 1) m = fmaxf(m, __shfl_xor(m, d));
    float p = __expf(acc - m);
    float s = p;
    for (int d = 32; d > 0; d >>= 1) s += __shfl_xor(s, d);
    __builtin_nontemporal_store(p / s, out + (size_t)row * 64 + lane);
}

// ---------------- launch ----------------

extern "C" void kernel_launch(void* const* d_in, const int* in_sizes, int n_in,
                              void* d_out, int out_size, void* d_ws, size_t ws_size,
                              hipStream_t stream) {
    const float* X    = (const float*)d_in[0];
    const int*   esrc = (const int*)d_in[1];
    const int*   edst = (const int*)d_in[2];
    const float* ewin = (const float*)d_in[3];
    const float* W0   = (const float*)d_in[4];
    const float* b0   = (const float*)d_in[5];
    const float* W1   = (const float*)d_in[6];
    const float* b1   = (const float*)d_in[7];
    const float* W2   = (const float*)d_in[8];
    const float* b2   = (const float*)d_in[9];
    float* out = (float*)d_out;

    const int N = GN;
    const int E = GE;

    uint8_t* p = (uint8_t*)d_ws;
    auto alloc = [&](size_t bytes) -> void* {
        void* r = (void*)p;
        p += (bytes + 255) & ~(size_t)255;
        return r;
    };
    _Float16* bufM  = (_Float16*)alloc((size_t)N * 512 * 2);   // GEMM out (fp16, gather table)
    _Float16* bufG  = (_Float16*)alloc((size_t)N * 512 * 2);   // spmm out H (fp16, next A)
    float*    bufC3 = (float*)alloc((size_t)N * 64 * 4);       // layer-3 logits (fp32)
    _Float16* W0th  = (_Float16*)alloc((size_t)512 * 512 * 2);
    _Float16* W0tl  = (_Float16*)alloc((size_t)512 * 512 * 2);
    _Float16* W1th  = (_Float16*)alloc((size_t)512 * 512 * 2);
    _Float16* W1tl  = (_Float16*)alloc((size_t)512 * 512 * 2);
    _Float16* W2th  = (_Float16*)alloc((size_t)64 * 512 * 2);
    _Float16* W2tl  = (_Float16*)alloc((size_t)64 * 512 * 2);
    int*   cnt     = (int*)alloc((size_t)N * 4);
    int*   row_ptr = (int*)alloc((size_t)(N + 1) * 4);
    int*   cursor  = (int*)alloc((size_t)N * 4);
    i32x2* epair   = (i32x2*)alloc((size_t)E * 8);
    int*   bsum    = (int*)alloc(1024 * 4);
    int*   boff    = (int*)alloc(1024 * 4);

    // CSR by dst (paired edges)
    int nch = (N + 511) / 512;
    k_zero<<<(N + 255) / 256, 256, 0, stream>>>(cnt, N);
    k_hist<<<2048, 256, 0, stream>>>(edst, cnt, E);
    k_chunksum<<<nch, 256, 0, stream>>>(cnt, bsum, N);
    k_scanb<<<1, 64, 0, stream>>>(bsum, boff, nch, row_ptr, N);
    k_scanw<<<nch, 512, 0, stream>>>(cnt, boff, row_ptr, cursor, N);
    k_scatter<<<2048, 256, 0, stream>>>(esrc, edst, ewin, cursor, epair, E);

    // weight split-transposes (hi/lo fp16) — split W needed on ALL layers (R11 lesson)
    k_transp_split<<<dim3(16, 16), dim3(32, 8), 0, stream>>>(W0, W0th, W0tl, 512, 512);
    k_transp_split<<<dim3(16, 16), dim3(32, 8), 0, stream>>>(W1, W1th, W1tl, 512, 512);
    k_transp_split<<<dim3(2, 16),  dim3(32, 8), 0, stream>>>(W2, W2th, W2tl, 512, 64);

    int gy = (N + 127) / 128;
    // layer 1: M = X @ W0 (fp32-A split x split-W, X/W0 never rounded)
    k_gemm_split<128, _Float16><<<dim3(4, gy), 256, 0, stream>>>(X, W0th, W0tl, bufM, N, 512);
    k_spmm512_h2h<<<N, 64, 0, stream>>>(row_ptr, epair, bufM, b0, bufG, 1);
    // layer 2: fp16 A x split-W (2 MFMA/pair), no spill at (256,2)
    k_gemm_f16w2<128, _Float16><<<dim3(4, gy), 256, 0, stream>>>(bufG, W1th, W1tl, bufM, N, 512);
    k_spmm512_h2h<<<N, 64, 0, stream>>>(row_ptr, epair, bufM, b1, bufG, 1);
    // layer 3 + softmax (fp32 logits)
    k_gemm_f16w2<64, float><<<dim3(1, gy), 256, 0, stream>>>(bufG, W2th, W2tl, bufC3, N, 64);
    k_spmm64_softmax<<<(N + 3) / 4, 256, 0, stream>>>(row_ptr, epair, bufC3, b2, out, N);
}

// Round 13
// 1630.498 us; speedup vs baseline: 1.0542x; 1.0168x over previous
//
#include <hip/hip_runtime.h>
#include <hip/hip_bf16.h>
#include <cstdint>
#include <cstddef>

#define GN 100000
#define GE 3200000

typedef __attribute__((ext_vector_type(8))) _Float16 f16x8;
typedef __attribute__((ext_vector_type(4))) _Float16 f16x4;
typedef __attribute__((ext_vector_type(4))) float f32x4;
typedef __attribute__((ext_vector_type(2))) int i32x2;   // NT-safe 8B edge pair

// ---------------- CSR build ----------------

__global__ void k_zero(int* __restrict__ p, int n) {
    int i = blockIdx.x * blockDim.x + threadIdx.x;
    if (i < n) p[i] = 0;
}

__global__ void k_hist(const int* __restrict__ dst, int* __restrict__ cnt, int e) {
    for (int i = blockIdx.x * blockDim.x + threadIdx.x; i < e; i += gridDim.x * blockDim.x)
        atomicAdd(&cnt[__builtin_nontemporal_load(dst + i)], 1);
}

__global__ void k_chunksum(const int* __restrict__ cnt, int* __restrict__ bsum, int n) {
    __shared__ int s[256];
    int b = blockIdx.x, t = threadIdx.x;
    int i0 = b * 512;
    int v = 0;
    int i1 = i0 + t;        if (i1 < n) v += cnt[i1];
    int i2 = i0 + 256 + t;  if (i2 < n) v += cnt[i2];
    s[t] = v; __syncthreads();
    for (int d = 128; d > 0; d >>= 1) {
        if (t < d) s[t] += s[t + d];
        __syncthreads();
    }
    if (t == 0) bsum[b] = s[0];
}

__global__ void k_scanb(const int* __restrict__ bsum, int* __restrict__ boff, int nb,
                        int* __restrict__ row_ptr, int n) {
    if (threadIdx.x == 0 && blockIdx.x == 0) {
        int acc = 0;
        for (int b = 0; b < nb; b++) { boff[b] = acc; acc += bsum[b]; }
        row_ptr[n] = acc;
    }
}

__global__ void k_scanw(const int* __restrict__ cnt, const int* __restrict__ boff,
                        int* __restrict__ row_ptr, int* __restrict__ cursor, int n) {
    __shared__ int s[512];
    int b = blockIdx.x, t = threadIdx.x;
    int i = b * 512 + t;
    int x = (i < n) ? cnt[i] : 0;
    s[t] = x; __syncthreads();
    for (int d = 1; d < 512; d <<= 1) {
        int v = (t >= d) ? s[t - d] : 0;
        __syncthreads();
        s[t] += v;
        __syncthreads();
    }
    int excl = s[t] - x + boff[b];
    if (i < n) { row_ptr[i] = excl; cursor[i] = excl; }
}

// paired scatter: one 8B store per edge (src, weight-bits)
__global__ void k_scatter(const int* __restrict__ src, const int* __restrict__ dst,
                          const float* __restrict__ w, int* __restrict__ cursor,
                          i32x2* __restrict__ epair, int e) {
    for (int i = blockIdx.x * blockDim.x + threadIdx.x; i < e; i += gridDim.x * blockDim.x) {
        int d = __builtin_nontemporal_load(dst + i);
        int p = atomicAdd(&cursor[d], 1);
        i32x2 v;
        v.x = __builtin_nontemporal_load(src + i);
        v.y = __float_as_int(__builtin_nontemporal_load(w + i));
        epair[p] = v;
    }
}

// ---------------- W[K][M] fp32 -> split-transposed Wth/Wtl[M][K] fp16 ----------------

__global__ void k_transp_split(const float* __restrict__ W,
                               _Float16* __restrict__ Wth, _Float16* __restrict__ Wtl,
                               int K, int M) {
    __shared__ float tile[32][33];
    int bx = blockIdx.x * 32;  // M dim
    int by = blockIdx.y * 32;  // K dim
    int tx = threadIdx.x, ty = threadIdx.y;
    for (int i = ty; i < 32; i += 8)
        tile[i][tx] = W[(size_t)(by + i) * M + bx + tx];
    __syncthreads();
    for (int i = ty; i < 32; i += 8) {
        float w = tile[tx][i];
        _Float16 h = (_Float16)w;
        _Float16 l = (_Float16)(w - (float)h);
        Wth[(size_t)(bx + i) * K + by + tx] = h;
        Wtl[(size_t)(bx + i) * K + by + tx] = l;
    }
}

// ---------------- fp32-A (rounded to fp16 on stage) x split-W GEMM: layer 1 ----------------
// acc = Ah*Bh + Ah*Bl (2 MFMA/pair). X rounds to fp16 once; W0 keeps ~22-bit.

template<int BN, typename OutT>
__global__ __launch_bounds__(256, 2) void k_gemm_f32a_w2(const float* __restrict__ A,
                                                         const _Float16* __restrict__ Bth,
                                                         const _Float16* __restrict__ Btl,
                                                         OutT* __restrict__ C,
                                                         int n, int m) {
    constexpr int NI  = BN / 32;
    constexpr int BIT = BN / 32;
    __shared__ _Float16 As[128 * 64];
    __shared__ _Float16 Bsh[BN * 64];
    __shared__ _Float16 Bsl[BN * 64];
    int tid = threadIdx.x;
    int wv = tid >> 6, lane = tid & 63;
    int wr = wv >> 1, wc = wv & 1;
    int r0 = blockIdx.y * 128;
    int c0 = blockIdx.x * BN;

    float4 areg[8];
    f16x8 bregh[BIT], bregl[BIT];
    f32x4 acc[4][NI];
    #pragma unroll
    for (int i = 0; i < 4; i++)
        #pragma unroll
        for (int j = 0; j < NI; j++)
            acc[i][j] = (f32x4){0.f, 0.f, 0.f, 0.f};

    auto aload = [&](int kt) {
        #pragma unroll
        for (int i = 0; i < 8; ++i) {
            int q = tid + 256 * i;
            int row = q >> 4, c4 = q & 15;
            int gr = r0 + row; if (gr >= n) gr = n - 1;
            areg[i] = *(const float4*)(A + (size_t)gr * 512 + kt * 64 + c4 * 4);
        }
        #pragma unroll
        for (int i = 0; i < BIT; ++i) {
            int q = tid + 256 * i;
            int col = q >> 3, c = q & 7;
            size_t off = (size_t)(c0 + col) * 512 + kt * 64 + c * 8;
            bregh[i] = *(const f16x8*)(Bth + off);
            bregl[i] = *(const f16x8*)(Btl + off);
        }
    };

    aload(0);
    for (int kt = 0; kt < 8; ++kt) {
        __syncthreads();
        #pragma unroll
        for (int i = 0; i < 8; ++i) {
            int q = tid + 256 * i;
            int row = q >> 4, c4 = q & 15;
            int g = c4 ^ ((row & 7) << 1);       // 8B-granule swizzle
            float4 a = areg[i];
            f16x4 h = { (_Float16)a.x, (_Float16)a.y, (_Float16)a.z, (_Float16)a.w };
            *(f16x4*)&As[row * 64 + g * 4] = h;
        }
        #pragma unroll
        for (int i = 0; i < BIT; ++i) {
            int q = tid + 256 * i;
            int col = q >> 3, c = q & 7;
            int idx = col * 64 + ((c ^ (col & 7)) * 8);
            *(f16x8*)&Bsh[idx] = bregh[i];
            *(f16x8*)&Bsl[idx] = bregl[i];
        }
        __syncthreads();
        if (kt < 7) aload(kt + 1);
        #pragma unroll
        for (int ks = 0; ks < 2; ++ks) {
            f16x8 af[4], bfh[NI], bfl[NI];
            int cch = ks * 4 + (lane >> 4);
            #pragma unroll
            for (int mi = 0; mi < 4; ++mi) {
                int row = wr * 64 + mi * 16 + (lane & 15);
                int idx = row * 64 + (((cch * 2) ^ ((row & 7) << 1)) * 4);
                af[mi] = *(const f16x8*)&As[idx];
            }
            #pragma unroll
            for (int ni = 0; ni < NI; ++ni) {
                int col = wc * (BN / 2) + ni * 16 + (lane & 15);
                int idx = col * 64 + ((cch ^ (col & 7)) * 8);
                bfh[ni] = *(const f16x8*)&Bsh[idx];
                bfl[ni] = *(const f16x8*)&Bsl[idx];
            }
            #pragma unroll
            for (int mi = 0; mi < 4; ++mi)
                #pragma unroll
                for (int ni = 0; ni < NI; ++ni) {
                    acc[mi][ni] = __builtin_amdgcn_mfma_f32_16x16x32_f16(
                        af[mi], bfl[ni], acc[mi][ni], 0, 0, 0);
                    acc[mi][ni] = __builtin_amdgcn_mfma_f32_16x16x32_f16(
                        af[mi], bfh[ni], acc[mi][ni], 0, 0, 0);
                }
        }
    }

    #pragma unroll
    for (int mi = 0; mi < 4; ++mi) {
        #pragma unroll
        for (int j = 0; j < 4; ++j) {
            int gr = r0 + wr * 64 + mi * 16 + (lane >> 4) * 4 + j;
            if (gr < n) {
                #pragma unroll
                for (int ni = 0; ni < NI; ++ni) {
                    int gc = c0 + wc * (BN / 2) + ni * 16 + (lane & 15);
                    C[(size_t)gr * m + gc] = (OutT)acc[mi][ni][j];
                }
            }
        }
    }
}

// ---------------- fp16-A, split-W MFMA GEMM (layers 2,3): 2 MFMA/pair, (256,2) ----------------

template<int BN, typename OutT>
__global__ __launch_bounds__(256, 2) void k_gemm_f16w2(const _Float16* __restrict__ A,
                                                       const _Float16* __restrict__ Bth,
                                                       const _Float16* __restrict__ Btl,
                                                       OutT* __restrict__ C,
                                                       int n, int m) {
    constexpr int NI  = BN / 32;
    constexpr int BIT = BN / 32;
    __shared__ _Float16 As[128 * 64];
    __shared__ _Float16 Bsh[BN * 64];
    __shared__ _Float16 Bsl[BN * 64];
    int tid = threadIdx.x;
    int wv = tid >> 6, lane = tid & 63;
    int wr = wv >> 1, wc = wv & 1;
    int r0 = blockIdx.y * 128;
    int c0 = blockIdx.x * BN;

    f16x8 areg[4], bregh[BIT], bregl[BIT];
    f32x4 acc[4][NI];
    #pragma unroll
    for (int i = 0; i < 4; i++)
        #pragma unroll
        for (int j = 0; j < NI; j++)
            acc[i][j] = (f32x4){0.f, 0.f, 0.f, 0.f};

    auto aload = [&](int kt) {
        #pragma unroll
        for (int i = 0; i < 4; ++i) {
            int q = tid + 256 * i;
            int row = q >> 3, c = q & 7;
            int gr = r0 + row; if (gr >= n) gr = n - 1;
            areg[i] = *(const f16x8*)(A + (size_t)gr * 512 + kt * 64 + c * 8);
        }
        #pragma unroll
        for (int i = 0; i < BIT; ++i) {
            int q = tid + 256 * i;
            int col = q >> 3, c = q & 7;
            size_t off = (size_t)(c0 + col) * 512 + kt * 64 + c * 8;
            bregh[i] = *(const f16x8*)(Bth + off);
            bregl[i] = *(const f16x8*)(Btl + off);
        }
    };

    aload(0);
    for (int kt = 0; kt < 8; ++kt) {
        __syncthreads();
        #pragma unroll
        for (int i = 0; i < 4; ++i) {
            int q = tid + 256 * i;
            int row = q >> 3, c = q & 7;
            *(f16x8*)&As[row * 64 + ((c ^ (row & 7)) * 8)] = areg[i];
        }
        #pragma unroll
        for (int i = 0; i < BIT; ++i) {
            int q = tid + 256 * i;
            int col = q >> 3, c = q & 7;
            int idx = col * 64 + ((c ^ (col & 7)) * 8);
            *(f16x8*)&Bsh[idx] = bregh[i];
            *(f16x8*)&Bsl[idx] = bregl[i];
        }
        __syncthreads();
        if (kt < 7) aload(kt + 1);
        #pragma unroll
        for (int ks = 0; ks < 2; ++ks) {
            f16x8 af[4], bfh[NI], bfl[NI];
            int cch = ks * 4 + (lane >> 4);
            #pragma unroll
            for (int mi = 0; mi < 4; ++mi) {
                int row = wr * 64 + mi * 16 + (lane & 15);
                af[mi] = *(const f16x8*)&As[row * 64 + ((cch ^ (row & 7)) * 8)];
            }
            #pragma unroll
            for (int ni = 0; ni < NI; ++ni) {
                int col = wc * (BN / 2) + ni * 16 + (lane & 15);
                int idx = col * 64 + ((cch ^ (col & 7)) * 8);
                bfh[ni] = *(const f16x8*)&Bsh[idx];
                bfl[ni] = *(const f16x8*)&Bsl[idx];
            }
            #pragma unroll
            for (int mi = 0; mi < 4; ++mi)
                #pragma unroll
                for (int ni = 0; ni < NI; ++ni) {
                    acc[mi][ni] = __builtin_amdgcn_mfma_f32_16x16x32_f16(
                        af[mi], bfl[ni], acc[mi][ni], 0, 0, 0);
                    acc[mi][ni] = __builtin_amdgcn_mfma_f32_16x16x32_f16(
                        af[mi], bfh[ni], acc[mi][ni], 0, 0, 0);
                }
        }
    }

    #pragma unroll
    for (int mi = 0; mi < 4; ++mi) {
        #pragma unroll
        for (int j = 0; j < 4; ++j) {
            int gr = r0 + wr * 64 + mi * 16 + (lane >> 4) * 4 + j;
            if (gr < n) {
                #pragma unroll
                for (int ni = 0; ni < NI; ++ni) {
                    int gc = c0 + wc * (BN / 2) + ni * 16 + (lane & 15);
                    C[(size_t)gr * m + gc] = (OutT)acc[mi][ni][j];
                }
            }
        }
    }
}

// ---------------- SpMM K=512: fp16 gather -> fp16 out (+bias, +relu), ILP 8 ----------------

__global__ __launch_bounds__(64) void k_spmm512_h2h(const int* __restrict__ rowp,
                                                    const i32x2* __restrict__ epair,
                                                    const _Float16* __restrict__ H,
                                                    const float* __restrict__ bias,
                                                    _Float16* __restrict__ out,
                                                    int relu) {
    int row = blockIdx.x;
    int t = threadIdx.x;                 // 64 threads, each owns 8 cols (f16x8)
    int s0 = rowp[row], s1 = rowp[row + 1];
    const f16x8* H8 = (const f16x8*)H;   // row stride 64 vectors
    float a0 = 0.f, a1 = 0.f, a2 = 0.f, a3 = 0.f;
    float a4 = 0.f, a5 = 0.f, a6 = 0.f, a7 = 0.f;
    __shared__ i32x2 le[64];
    for (int base = s0; base < s1; base += 64) {
        int nn = s1 - base; if (nn > 64) nn = 64;
        __syncthreads();
        if (t < nn) le[t] = __builtin_nontemporal_load(epair + base + t);
        __syncthreads();
        int e = 0;
        for (; e + 8 <= nn; e += 8) {      // 8 outstanding 1KB wave-gathers
            i32x2 p0 = le[e],     p1 = le[e + 1], p2 = le[e + 2], p3 = le[e + 3];
            i32x2 p4 = le[e + 4], p5 = le[e + 5], p6 = le[e + 6], p7 = le[e + 7];
            f16x8 h0 = H8[(size_t)p0.x * 64 + t];
            f16x8 h1 = H8[(size_t)p1.x * 64 + t];
            f16x8 h2 = H8[(size_t)p2.x * 64 + t];
            f16x8 h3 = H8[(size_t)p3.x * 64 + t];
            f16x8 h4 = H8[(size_t)p4.x * 64 + t];
            f16x8 h5 = H8[(size_t)p5.x * 64 + t];
            f16x8 h6 = H8[(size_t)p6.x * 64 + t];
            f16x8 h7 = H8[(size_t)p7.x * 64 + t];
            float w0 = __int_as_float(p0.y), w1 = __int_as_float(p1.y);
            float w2 = __int_as_float(p2.y), w3 = __int_as_float(p3.y);
            float w4 = __int_as_float(p4.y), w5 = __int_as_float(p5.y);
            float w6 = __int_as_float(p6.y), w7 = __int_as_float(p7.y);
            a0 += w0*(float)h0[0] + w1*(float)h1[0] + w2*(float)h2[0] + w3*(float)h3[0]
                + w4*(float)h4[0] + w5*(float)h5[0] + w6*(float)h6[0] + w7*(float)h7[0];
            a1 += w0*(float)h0[1] + w1*(float)h1[1] + w2*(float)h2[1] + w3*(float)h3[1]
                + w4*(float)h4[1] + w5*(float)h5[1] + w6*(float)h6[1] + w7*(float)h7[1];
            a2 += w0*(float)h0[2] + w1*(float)h1[2] + w2*(float)h2[2] + w3*(float)h3[2]
                + w4*(float)h4[2] + w5*(float)h5[2] + w6*(float)h6[2] + w7*(float)h7[2];
            a3 += w0*(float)h0[3] + w1*(float)h1[3] + w2*(float)h2[3] + w3*(float)h3[3]
                + w4*(float)h4[3] + w5*(float)h5[3] + w6*(float)h6[3] + w7*(float)h7[3];
            a4 += w0*(float)h0[4] + w1*(float)h1[4] + w2*(float)h2[4] + w3*(float)h3[4]
                + w4*(float)h4[4] + w5*(float)h5[4] + w6*(float)h6[4] + w7*(float)h7[4];
            a5 += w0*(float)h0[5] + w1*(float)h1[5] + w2*(float)h2[5] + w3*(float)h3[5]
                + w4*(float)h4[5] + w5*(float)h5[5] + w6*(float)h6[5] + w7*(float)h7[5];
            a6 += w0*(float)h0[6] + w1*(float)h1[6] + w2*(float)h2[6] + w3*(float)h3[6]
                + w4*(float)h4[6] + w5*(float)h5[6] + w6*(float)h6[6] + w7*(float)h7[6];
            a7 += w0*(float)h0[7] + w1*(float)h1[7] + w2*(float)h2[7] + w3*(float)h3[7]
                + w4*(float)h4[7] + w5*(float)h5[7] + w6*(float)h6[7] + w7*(float)h7[7];
        }
        for (; e < nn; ++e) {
            i32x2 pe = le[e];
            f16x8 h = H8[(size_t)pe.x * 64 + t]; float w = __int_as_float(pe.y);
            a0 += w * (float)h[0]; a1 += w * (float)h[1];
            a2 += w * (float)h[2]; a3 += w * (float)h[3];
            a4 += w * (float)h[4]; a5 += w * (float)h[5];
            a6 += w * (float)h[6]; a7 += w * (float)h[7];
        }
    }
    const float4* b4 = (const float4*)bias;
    float4 blo = b4[t * 2], bhi = b4[t * 2 + 1];
    a0 += blo.x; a1 += blo.y; a2 += blo.z; a3 += blo.w;
    a4 += bhi.x; a5 += bhi.y; a6 += bhi.z; a7 += bhi.w;
    if (relu) {
        a0 = fmaxf(a0, 0.f); a1 = fmaxf(a1, 0.f); a2 = fmaxf(a2, 0.f); a3 = fmaxf(a3, 0.f);
        a4 = fmaxf(a4, 0.f); a5 = fmaxf(a5, 0.f); a6 = fmaxf(a6, 0.f); a7 = fmaxf(a7, 0.f);
    }
    f16x8 o = { (_Float16)a0, (_Float16)a1, (_Float16)a2, (_Float16)a3,
                (_Float16)a4, (_Float16)a5, (_Float16)a6, (_Float16)a7 };
    ((f16x8*)out)[(size_t)row * 64 + t] = o;
}

// ---------------- SpMM K=64 fp32 + bias + softmax, one wave per dst row ----------------

__global__ __launch_bounds__(256) void k_spmm64_softmax(const int* __restrict__ rowp,
                                                        const i32x2* __restrict__ epair,
                                                        const float* __restrict__ H,
                                                        const float* __restrict__ bias,
                                                        float* __restrict__ out, int n) {
    int wid  = threadIdx.x >> 6;
    int lane = threadIdx.x & 63;
    int row  = blockIdx.x * 4 + wid;
    if (row >= n) return;
    int s0 = rowp[row], s1 = rowp[row + 1];
    float acc = 0.f;
    int e = s0;
    for (; e + 4 <= s1; e += 4) {
        i32x2 p0 = epair[e],     p1 = epair[e + 1];
        i32x2 p2 = epair[e + 2], p3 = epair[e + 3];
        float h0 = H[(size_t)p0.x * 64 + lane];
        float h1 = H[(size_t)p1.x * 64 + lane];
        float h2 = H[(size_t)p2.x * 64 + lane];
        float h3 = H[(size_t)p3.x * 64 + lane];
        acc += __int_as_float(p0.y) * h0 + __int_as_float(p1.y) * h1
             + __int_as_float(p2.y) * h2 + __int_as_float(p3.y) * h3;
    }
    for (; e < s1; ++e) {
        i32x2 pe = epair[e];
        acc += __int_as_float(pe.y) * H[(size_t)pe.x * 64 + lane];
    }
    acc += bias[lane];
    float m = acc;
    for (int d = 32; d > 0; d >>= 1) m = fmaxf(m, __shfl_xor(m, d));
    float p = __expf(acc - m);
    float s = p;
    for (int d = 32; d > 0; d >>= 1) s += __shfl_xor(s, d);
    __builtin_nontemporal_store(p / s, out + (size_t)row * 64 + lane);
}

// ---------------- launch ----------------

extern "C" void kernel_launch(void* const* d_in, const int* in_sizes, int n_in,
                              void* d_out, int out_size, void* d_ws, size_t ws_size,
                              hipStream_t stream) {
    const float* X    = (const float*)d_in[0];
    const int*   esrc = (const int*)d_in[1];
    const int*   edst = (const int*)d_in[2];
    const float* ewin = (const float*)d_in[3];
    const float* W0   = (const float*)d_in[4];
    const float* b0   = (const float*)d_in[5];
    const float* W1   = (const float*)d_in[6];
    const float* b1   = (const float*)d_in[7];
    const float* W2   = (const float*)d_in[8];
    const float* b2   = (const float*)d_in[9];
    float* out = (float*)d_out;

    const int N = GN;
    const int E = GE;

    uint8_t* p = (uint8_t*)d_ws;
    auto alloc = [&](size_t bytes) -> void* {
        void* r = (void*)p;
        p += (bytes + 255) & ~(size_t)255;
        return r;
    };
    _Float16* bufM  = (_Float16*)alloc((size_t)N * 512 * 2);   // GEMM out (fp16, gather table)
    _Float16* bufG  = (_Float16*)alloc((size_t)N * 512 * 2);   // spmm out H (fp16, next A)
    float*    bufC3 = (float*)alloc((size_t)N * 64 * 4);       // layer-3 logits (fp32)
    _Float16* W0th  = (_Float16*)alloc((size_t)512 * 512 * 2);
    _Float16* W0tl  = (_Float16*)alloc((size_t)512 * 512 * 2);
    _Float16* W1th  = (_Float16*)alloc((size_t)512 * 512 * 2);
    _Float16* W1tl  = (_Float16*)alloc((size_t)512 * 512 * 2);
    _Float16* W2th  = (_Float16*)alloc((size_t)64 * 512 * 2);
    _Float16* W2tl  = (_Float16*)alloc((size_t)64 * 512 * 2);
    int*   cnt     = (int*)alloc((size_t)N * 4);
    int*   row_ptr = (int*)alloc((size_t)(N + 1) * 4);
    int*   cursor  = (int*)alloc((size_t)N * 4);
    i32x2* epair   = (i32x2*)alloc((size_t)E * 8);
    int*   bsum    = (int*)alloc(1024 * 4);
    int*   boff    = (int*)alloc(1024 * 4);

    // CSR by dst (paired edges)
    int nch = (N + 511) / 512;
    k_zero<<<(N + 255) / 256, 256, 0, stream>>>(cnt, N);
    k_hist<<<2048, 256, 0, stream>>>(edst, cnt, E);
    k_chunksum<<<nch, 256, 0, stream>>>(cnt, bsum, N);
    k_scanb<<<1, 64, 0, stream>>>(bsum, boff, nch, row_ptr, N);
    k_scanw<<<nch, 512, 0, stream>>>(cnt, boff, row_ptr, cursor, N);
    k_scatter<<<2048, 256, 0, stream>>>(esrc, edst, ewin, cursor, epair, E);

    // weight split-transposes (hi/lo fp16) — split W on ALL layers (R11 lesson)
    k_transp_split<<<dim3(16, 16), dim3(32, 8), 0, stream>>>(W0, W0th, W0tl, 512, 512);
    k_transp_split<<<dim3(16, 16), dim3(32, 8), 0, stream>>>(W1, W1th, W1tl, 512, 512);
    k_transp_split<<<dim3(2, 16),  dim3(32, 8), 0, stream>>>(W2, W2th, W2tl, 512, 64);

    int gy = (N + 127) / 128;
    // layer 1: M = X @ W0 (X rounds to fp16 on stage; W0 split ~22-bit; 2 MFMA/pair)
    k_gemm_f32a_w2<128, _Float16><<<dim3(4, gy), 256, 0, stream>>>(X, W0th, W0tl, bufM, N, 512);
    k_spmm512_h2h<<<N, 64, 0, stream>>>(row_ptr, epair, bufM, b0, bufG, 1);
    // layer 2: fp16 A x split-W (2 MFMA/pair)
    k_gemm_f16w2<128, _Float16><<<dim3(4, gy), 256, 0, stream>>>(bufG, W1th, W1tl, bufM, N, 512);
    k_spmm512_h2h<<<N, 64, 0, stream>>>(row_ptr, epair, bufM, b1, bufG, 1);
    // layer 3 + softmax (fp32 logits)
    k_gemm_f16w2<64, float><<<dim3(1, gy), 256, 0, stream>>>(bufG, W2th, W2tl, bufC3, N, 64);
    k_spmm64_softmax<<<(N + 3) / 4, 256, 0, stream>>>(row_ptr, epair, bufC3, b2, out, N);
}